// Round 4
// baseline (3880.467 us; speedup 1.0000x reference)
//
#include <hip/hip_runtime.h>
#include <cstdint>
#include <cstddef>

typedef _Float16 f16;
typedef _Float16 half8 __attribute__((ext_vector_type(8)));
typedef _Float16 half4 __attribute__((ext_vector_type(4)));
typedef float f32x4 __attribute__((ext_vector_type(4)));

#define NB 256   // batch
#define NT 64    // time
#define NE 1024  // input dim
#define NH 1024  // hidden
#define NZ 512   // out dim
#define NG 4096  // 4*NH

// XOR swizzle for 128B-row LDS tiles (k_gemm): row bits [9:7]
__device__ __forceinline__ int swz(int b) { return b ^ (((b >> 7) & 7) << 4); }
// XOR swizzle for 2048B-row LDS tiles (k_rnn A = h[32][1024] fp16): row bits [13:11]
__device__ __forceinline__ int swza(int b) { return b ^ (((b >> 11) & 7) << 4); }

#define GL_LDS16(gp, lp)                                                          \
  __builtin_amdgcn_global_load_lds((__attribute__((address_space(1))) void*)(gp), \
                                   (__attribute__((address_space(3))) void*)(lp), \
                                   16, 0, 0)

__device__ __forceinline__ float sigm(float x) { return 1.f / (1.f + __expf(-x)); }

// ---------------- prep kernels ----------------
__global__ __launch_bounds__(256) void k_cvt(const float* __restrict__ s, f16* __restrict__ d) {
  int i = (blockIdx.x * 256 + threadIdx.x) * 4;
  float4 v = *(const float4*)(s + i);
  half4 h;
  h[0] = (f16)v.x; h[1] = (f16)v.y; h[2] = (f16)v.z; h[3] = (f16)v.w;
  *(half4*)(d + i) = h;
}

__global__ __launch_bounds__(256) void k_addcvt(const float* __restrict__ a,
                                                const float* __restrict__ b,
                                                f16* __restrict__ d) {
  int i = (blockIdx.x * 256 + threadIdx.x) * 4;
  float4 va = *(const float4*)(a + i);
  float4 vb = *(const float4*)(b + i);
  half4 h;
  h[0] = (f16)(va.x + vb.x); h[1] = (f16)(va.y + vb.y);
  h[2] = (f16)(va.z + vb.z); h[3] = (f16)(va.w + vb.w);
  *(half4*)(d + i) = h;
}

__global__ __launch_bounds__(256) void k_bias(const float* be1, const float* be2,
                                              const float* bd1, const float* bd2,
                                              float* be, float* bd) {
  int i = blockIdx.x * 256 + threadIdx.x;  // grid 16 -> 4096
  be[i] = be1[i] + be2[i];
  bd[i] = bd1[i] + bd2[i];
}

// bd0[r] = bd[r] + 0.1 * sum_k W_ih_d[r][k]   (decoder step-0 constant input)
__global__ __launch_bounds__(256) void k_bd0(const float* __restrict__ Wihd,
                                             const float* __restrict__ bd,
                                             float* __restrict__ bd0) {
  int wglob = (blockIdx.x * 256 + threadIdx.x) >> 6;  // grid 64 -> 256 waves
  int lane = threadIdx.x & 63;
  for (int it = 0; it < 16; ++it) {
    int r = it * 256 + wglob;
    const float* row = Wihd + (size_t)r * NH;
    float s = 0.f;
    for (int k = lane; k < NH; k += 64) s += row[k];
    for (int o = 32; o; o >>= 1) s += __shfl_down(s, o);
    if (lane == 0) bd0[r] = bd[r] + 0.1f * s;
  }
}

__global__ __launch_bounds__(256) void k_init(f16* hb, unsigned* bar) {
  int i = blockIdx.x * 256 + threadIdx.x;  // grid 1024 -> 262144
  hb[i] = (f16)0.f;
  if (i < 256) bar[i] = 0u;
}

// ---------------- generic NT GEMM (unchanged; passed R1) ----------------
template <int EPI>
__global__ __launch_bounds__(256) void k_gemm(const f16* __restrict__ A,
                                              const f16* __restrict__ Bm,
                                              const float* __restrict__ bias,
                                              f16* __restrict__ outH,
                                              float* __restrict__ outF,
                                              int M, int N, int K) {
  __shared__ char lds[32768];  // A 16KB @0, B 16KB @16384
  const int tid = threadIdx.x;
  const int lane = tid & 63, wid = tid >> 6;
  const int wm = wid >> 1, wn = wid & 1;
  const int bm = blockIdx.y * 128, bn = blockIdx.x * 128;
  const int l15 = lane & 15, l4 = lane >> 4;

  f32x4 acc[4][4] = {};

  for (int k0 = 0; k0 < K; k0 += 64) {
#pragma unroll
    for (int q = 0; q < 4; ++q) {
      int P = (q * 256 + tid) * 16;
      int L = swz(P);
      int row = L >> 7, col = (L & 127) >> 1;
      GL_LDS16(A + (size_t)(bm + row) * K + k0 + col, lds + P);
      GL_LDS16(Bm + (size_t)(bn + row) * K + k0 + col, lds + 16384 + P);
    }
    __syncthreads();
#pragma unroll
    for (int kk = 0; kk < 2; ++kk) {
      half8 af[4], bf[4];
#pragma unroll
      for (int mi = 0; mi < 4; ++mi) {
        int L = (wm * 64 + mi * 16 + l15) * 128 + (kk * 32 + l4 * 8) * 2;
        af[mi] = *(const half8*)(lds + swz(L));
      }
#pragma unroll
      for (int ni = 0; ni < 4; ++ni) {
        int L = (wn * 64 + ni * 16 + l15) * 128 + (kk * 32 + l4 * 8) * 2;
        bf[ni] = *(const half8*)(lds + 16384 + swz(L));
      }
#pragma unroll
      for (int mi = 0; mi < 4; ++mi)
#pragma unroll
        for (int ni = 0; ni < 4; ++ni)
          acc[mi][ni] = __builtin_amdgcn_mfma_f32_16x16x32_f16(af[mi], bf[ni], acc[mi][ni], 0, 0, 0);
    }
    __syncthreads();
  }

#pragma unroll
  for (int mi = 0; mi < 4; ++mi)
#pragma unroll
    for (int ni = 0; ni < 4; ++ni)
#pragma unroll
      for (int e = 0; e < 4; ++e) {
        int m = bm + wm * 64 + mi * 16 + l4 * 4 + e;
        int n = bn + wn * 64 + ni * 16 + l15;
        float v = acc[mi][ni][e] + bias[n];
        if constexpr (EPI == 0) {
          outH[(size_t)m * N + n] = (f16)v;
        } else {
          int b = m & 255, t = m >> 8;
          outF[(size_t)b * (NT * NZ) + t * NZ + n] = tanhf(v);
        }
      }
}

// ---------------- persistent recurrent kernel ----------------
// 256 blocks x 512 thr (8 waves), 1 block/CU. Block bid: bg = bid&7 (batch
// group, 32 rows), ug = bid>>3 (unit group, 32 units). Wave wid: g = wid>>1
// (gate), uh = wid&1 (unit half of 16). W fragments live in 128 VGPRs/lane;
// c[32][32] lives in LDS for all 128 steps. Cross-block dataflow is entirely
// within a bg-group (32 blocks) -> per-bg 32-arrival barrier. NOTE: groups
// pace independently -> NO buffer written by one group may be read by another
// group at a different logical step (R2 bug: Hs aliased Xg; now Hs = x16,
// which is dead after k_gemm<0>).
//
// LDS: A(h tile, swizzled) 64KB @0 | gate exch 16KB @65536 | c 4KB @81920

__device__ __forceinline__ void loadW(half8* breg, const f16* __restrict__ W,
                                      int row, int l4) {
  const f16* p = W + (size_t)row * NH + l4 * 8;
#pragma unroll
  for (int kf = 0; kf < 32; ++kf) breg[kf] = *(const half8*)(p + kf * 32);
}

__device__ __forceinline__ void gsync(unsigned* bar, unsigned target) {
  __syncthreads();  // each wave drains vmcnt(0): all h2 stores in L2 before release
  if (threadIdx.x == 0) {
    __hip_atomic_fetch_add(bar, 1u, __ATOMIC_ACQ_REL, __HIP_MEMORY_SCOPE_AGENT);
    while (__hip_atomic_load(bar, __ATOMIC_ACQUIRE, __HIP_MEMORY_SCOPE_AGENT) < target) {}
  }
  __syncthreads();
  __builtin_amdgcn_fence(__ATOMIC_ACQUIRE, "agent");  // every wave invalidates caches
}

template <bool ENC>
__device__ __forceinline__ void lstm_step(const f16* __restrict__ hi, f16* __restrict__ ho,
                                          const half8* breg, char* ldsb,
                                          const f16* __restrict__ xg0,
                                          const f16* __restrict__ xg1,
                                          const float* bias4, int bg, int ug, int tid,
                                          int l15, int l4, int g, int uh) {
  float pre[8];
  if constexpr (ENC) {  // issue early: HBM latency hides under staging+MFMA
#pragma unroll
    for (int i = 0; i < 4; ++i) {
      pre[i] = (float)xg0[i * 1024];
      pre[4 + i] = (float)xg1[i * 1024];
    }
  } else {
#pragma unroll
    for (int i = 0; i < 4; ++i) { pre[i] = bias4[i]; pre[4 + i] = bias4[i]; }
  }
  // stage h[bg*32 .. +32][0..1024] -> LDS A (linear dest, inverse-swizzled src)
#pragma unroll
  for (int it = 0; it < 8; ++it) {
    int P = (it * 512 + tid) * 16;
    int L = swza(P);
    GL_LDS16(hi + (size_t)(bg * 32 + (L >> 11)) * NH + ((L & 2047) >> 1), ldsb + P);
  }
  __syncthreads();

  f32x4 acc0 = {}, acc1 = {};
#pragma unroll
  for (int kf = 0; kf < 32; ++kf) {
    int L0 = l15 * 2048 + kf * 64 + l4 * 16;
    half8 a0 = *(const half8*)(ldsb + swza(L0));
    half8 a1 = *(const half8*)(ldsb + swza(L0 + 32768));
    acc0 = __builtin_amdgcn_mfma_f32_16x16x32_f16(a0, breg[kf], acc0, 0, 0, 0);
    acc1 = __builtin_amdgcn_mfma_f32_16x16x32_f16(a1, breg[kf], acc1, 0, 0, 0);
  }

  float* ex = (float*)(ldsb + 65536);  // [4 g][32 b][32 u]
  float* cc = (float*)(ldsb + 81920);  // [32 b][32 u]
#pragma unroll
  for (int e = 0; e < 4; ++e) {
    ex[g * 1024 + (l4 * 4 + e) * 32 + uh * 16 + l15] = acc0[e];
    ex[g * 1024 + (16 + l4 * 4 + e) * 32 + uh * 16 + l15] = acc1[e];
  }
  __syncthreads();

#pragma unroll
  for (int hf = 0; hf < 2; ++hf) {
    int ci = hf * 512 + tid;  // b = ci>>5, u = ci&31
    float v0 = ex[ci] + pre[hf * 4 + 0];
    float v1 = ex[1024 + ci] + pre[hf * 4 + 1];
    float v2 = ex[2048 + ci] + pre[hf * 4 + 2];
    float v3 = ex[3072 + ci] + pre[hf * 4 + 3];
    float i_ = sigm(v0), f_ = sigm(v1), gg = tanhf(v2), o_ = sigm(v3);
    float c2 = f_ * cc[ci] + i_ * gg;
    cc[ci] = c2;
    ho[(size_t)(bg * 32 + (ci >> 5)) * NH + ug * 32 + (ci & 31)] = (f16)(o_ * tanhf(c2));
  }
}

__global__ __launch_bounds__(512, 2) void k_rnn(const f16* __restrict__ Whhe,
                                                const f16* __restrict__ Whhd,
                                                const f16* __restrict__ Wsum,
                                                const f16* __restrict__ Xg,
                                                const float* __restrict__ bd0v,
                                                const float* __restrict__ bdv,
                                                f16* __restrict__ hb0,
                                                f16* __restrict__ hb1,
                                                f16* __restrict__ Hs,
                                                unsigned* bar) {
  __shared__ __align__(16) char ldsb[86016];
  const int tid = threadIdx.x, lane = tid & 63, wid = tid >> 6;
  const int l15 = lane & 15, l4 = lane >> 4;
  const int bid = blockIdx.x, bg = bid & 7, ug = bid >> 3;
  const int g = wid >> 1, uh = wid & 1;
  const int u0 = tid & 31, b0 = tid >> 5;

  float* cc = (float*)(ldsb + 81920);
  cc[tid] = 0.f;
  cc[512 + tid] = 0.f;

  unsigned* mybar = bar + bg * 32;  // 8 counters, 128B apart
  unsigned gen = 0;
  const int wrow = g * 1024 + ug * 32 + uh * 16 + l15;

  half8 breg[32];
  loadW(breg, Whhe, wrow, l4);

  // -------- encoder: 64 steps, h ping-pong hb0/hb1 --------
  f16* hi = hb0;
  f16* ho = hb1;
  for (int t = 0; t < NT; ++t) {
    const f16* xg0 = Xg + ((size_t)(bg * 32 + b0) * NT + t) * NG + ug * 32 + u0;
    const f16* xg1 = xg0 + (size_t)16 * NT * NG;
    lstm_step<true>(hi, ho, breg, ldsb, xg0, xg1, nullptr, bg, ug, tid, l15, l4, g, uh);
    ++gen;
    gsync(mybar, gen * 32u);
    f16* tmp = hi; hi = ho; ho = tmp;
  }
  // encoder final h now in hi (= hb0)

  // -------- decoder step 0: W_hh_d, bias bd0 (0.1-input folded) --------
  loadW(breg, Whhd, wrow, l4);
  float bias4[4];
#pragma unroll
  for (int i = 0; i < 4; ++i) bias4[i] = bd0v[i * 1024 + ug * 32 + u0];
  lstm_step<false>(hi, Hs, breg, ldsb, nullptr, nullptr, bias4, bg, ug, tid, l15, l4, g, uh);
  ++gen;
  gsync(mybar, gen * 32u);

  // -------- decoder steps 1..63: W_ih_d + W_hh_d (inp == h), bias bd --------
  loadW(breg, Wsum, wrow, l4);
#pragma unroll
  for (int i = 0; i < 4; ++i) bias4[i] = bdv[i * 1024 + ug * 32 + u0];
  for (int t = 1; t < NT; ++t) {
    lstm_step<false>(Hs + (size_t)(t - 1) * NB * NH, Hs + (size_t)t * NB * NH, breg, ldsb,
                     nullptr, nullptr, bias4, bg, ug, tid, l15, l4, g, uh);
    if (t != NT - 1) {
      ++gen;
      gsync(mybar, gen * 32u);
    }
  }
}

// ---------------- workspace layout ----------------
// x16 (32MB) is dead after k_gemm<0>; Hs [T][B][H] fp16 (exactly 32MB) reuses it.
static const size_t OFF_X16  = 0;
static const size_t OFF_WIHE = OFF_X16 + (size_t)NB * NT * NE * 2;
static const size_t OFF_WHHE = OFF_WIHE + (size_t)NG * NH * 2;
static const size_t OFF_WSUM = OFF_WHHE + (size_t)NG * NH * 2;
static const size_t OFF_WHHD = OFF_WSUM + (size_t)NG * NH * 2;
static const size_t OFF_WZ   = OFF_WHHD + (size_t)NG * NH * 2;
static const size_t OFF_BE   = OFF_WZ + (size_t)NZ * NH * 2;
static const size_t OFF_BD   = OFF_BE + NG * 4;
static const size_t OFF_BD0  = OFF_BD + NG * 4;
static const size_t OFF_HB0  = OFF_BD0 + NG * 4;
static const size_t OFF_HB1  = OFF_HB0 + (size_t)NB * NH * 2;
static const size_t OFF_BAR  = OFF_HB1 + (size_t)NB * NH * 2;
static const size_t OFF_XG   = OFF_BAR + 4096;  // Xg [B][T][4H] fp16 (read-only in k_rnn)
static const size_t WS_TOTAL = OFF_XG + (size_t)NB * NT * NG * 2;  // ~193 MiB

extern "C" void kernel_launch(void* const* d_in, const int* in_sizes, int n_in,
                              void* d_out, int out_size, void* d_ws, size_t ws_size,
                              hipStream_t stream) {
  (void)in_sizes; (void)n_in; (void)out_size;
  const float* x    = (const float*)d_in[0];
  const float* Wihe = (const float*)d_in[1];
  const float* Whhe = (const float*)d_in[2];
  const float* bihe = (const float*)d_in[3];
  const float* bhhe = (const float*)d_in[4];
  const float* Wihd = (const float*)d_in[5];
  const float* Whhd = (const float*)d_in[6];
  const float* bihd = (const float*)d_in[7];
  const float* bhhd = (const float*)d_in[8];
  const float* Wzf  = (const float*)d_in[9];
  const float* bz   = (const float*)d_in[10];
  float* out = (float*)d_out;

  if (ws_size < WS_TOTAL) return;

  char* ws = (char*)d_ws;
  f16* x16    = (f16*)(ws + OFF_X16);
  f16* Wihe16 = (f16*)(ws + OFF_WIHE);
  f16* Whhe16 = (f16*)(ws + OFF_WHHE);
  f16* Wsum16 = (f16*)(ws + OFF_WSUM);
  f16* Whhd16 = (f16*)(ws + OFF_WHHD);
  f16* Wz16   = (f16*)(ws + OFF_WZ);
  float* be   = (float*)(ws + OFF_BE);
  float* bd   = (float*)(ws + OFF_BD);
  float* bd0  = (float*)(ws + OFF_BD0);
  f16* hb0    = (f16*)(ws + OFF_HB0);
  f16* hb1    = (f16*)(ws + OFF_HB1);
  unsigned* bar = (unsigned*)(ws + OFF_BAR);
  f16* Xg     = (f16*)(ws + OFF_XG);
  f16* Hs     = x16;  // decoder h history overlays dead x16 (NOT Xg — R2 bug)

  // prep
  k_cvt<<<(NB * NT * NE) / 1024, 256, 0, stream>>>(x, x16);
  k_cvt<<<(NG * NH) / 1024, 256, 0, stream>>>(Wihe, Wihe16);
  k_cvt<<<(NG * NH) / 1024, 256, 0, stream>>>(Whhe, Whhe16);
  k_cvt<<<(NG * NH) / 1024, 256, 0, stream>>>(Whhd, Whhd16);
  k_cvt<<<(NZ * NH) / 1024, 256, 0, stream>>>(Wzf, Wz16);
  k_addcvt<<<(NG * NH) / 1024, 256, 0, stream>>>(Wihd, Whhd, Wsum16);
  k_bias<<<NG / 256, 256, 0, stream>>>(bihe, bhhe, bihd, bhhd, be, bd);
  k_bd0<<<64, 256, 0, stream>>>(Wihd, bd, bd0);
  k_init<<<(NB * NH) / 256, 256, 0, stream>>>(hb0, bar);

  // Xg = x @ W_ih_e^T + be   -> fp16 [B][T][4H]
  dim3 gx(NG / 128, (NB * NT) / 128);
  k_gemm<0><<<gx, 256, 0, stream>>>(x16, Wihe16, be, Xg, nullptr, NB * NT, NG, NE);

  // persistent recurrent kernel (cooperative: guarantees co-residency for barriers)
  void* kargs[10];
  kargs[0] = &Whhe16; kargs[1] = &Whhd16; kargs[2] = &Wsum16; kargs[3] = &Xg;
  kargs[4] = &bd0; kargs[5] = &bd; kargs[6] = &hb0; kargs[7] = &hb1;
  kargs[8] = &Hs; kargs[9] = &bar;
  hipLaunchCooperativeKernel((const void*)k_rnn, dim3(256), dim3(512), kargs, 0, stream);

  // z = tanh(Hs @ Wz^T + bz), scattered [t*256+b] -> out[b][t][:]
  dim3 gz(NZ / 128, (NB * NT) / 128);
  k_gemm<1><<<gz, 256, 0, stream>>>(Hs, Wz16, bz, nullptr, out, NB * NT, NZ, NH);
}

// Round 5
// 1104.664 us; speedup vs baseline: 3.5128x; 3.5128x over previous
//
#include <hip/hip_runtime.h>
#include <cstdint>
#include <cstddef>

typedef _Float16 f16;
typedef _Float16 half8 __attribute__((ext_vector_type(8)));
typedef _Float16 half4 __attribute__((ext_vector_type(4)));
typedef float f32x4 __attribute__((ext_vector_type(4)));

#define NB 256   // batch
#define NT 64    // time
#define NE 1024  // input dim
#define NH 1024  // hidden
#define NZ 512   // out dim
#define NG 4096  // 4*NH

// XOR swizzle for 128B-row LDS tiles (k_gemm): row bits [9:7]
__device__ __forceinline__ int swz(int b) { return b ^ (((b >> 7) & 7) << 4); }
// XOR swizzle for 2048B-row LDS tiles (k_rnn A = h[32][1024] fp16): row bits [13:11]
__device__ __forceinline__ int swza(int b) { return b ^ (((b >> 11) & 7) << 4); }

#define GL_LDS16(gp, lp)                                                          \
  __builtin_amdgcn_global_load_lds((__attribute__((address_space(1))) void*)(gp), \
                                   (__attribute__((address_space(3))) void*)(lp), \
                                   16, 0, 0)

__device__ __forceinline__ float sigm(float x) { return 1.f / (1.f + __expf(-x)); }

// ---------------- prep kernels ----------------
__global__ __launch_bounds__(256) void k_cvt(const float* __restrict__ s, f16* __restrict__ d) {
  int i = (blockIdx.x * 256 + threadIdx.x) * 4;
  float4 v = *(const float4*)(s + i);
  half4 h;
  h[0] = (f16)v.x; h[1] = (f16)v.y; h[2] = (f16)v.z; h[3] = (f16)v.w;
  *(half4*)(d + i) = h;
}

__global__ __launch_bounds__(256) void k_addcvt(const float* __restrict__ a,
                                                const float* __restrict__ b,
                                                f16* __restrict__ d) {
  int i = (blockIdx.x * 256 + threadIdx.x) * 4;
  float4 va = *(const float4*)(a + i);
  float4 vb = *(const float4*)(b + i);
  half4 h;
  h[0] = (f16)(va.x + vb.x); h[1] = (f16)(va.y + vb.y);
  h[2] = (f16)(va.z + vb.z); h[3] = (f16)(va.w + vb.w);
  *(half4*)(d + i) = h;
}

__global__ __launch_bounds__(256) void k_bias(const float* be1, const float* be2,
                                              const float* bd1, const float* bd2,
                                              float* be, float* bd) {
  int i = blockIdx.x * 256 + threadIdx.x;  // grid 16 -> 4096
  be[i] = be1[i] + be2[i];
  bd[i] = bd1[i] + bd2[i];
}

// bd0[r] = bd[r] + 0.1 * sum_k W_ih_d[r][k]   (decoder step-0 constant input)
__global__ __launch_bounds__(256) void k_bd0(const float* __restrict__ Wihd,
                                             const float* __restrict__ bd,
                                             float* __restrict__ bd0) {
  int wglob = (blockIdx.x * 256 + threadIdx.x) >> 6;  // grid 64 -> 256 waves
  int lane = threadIdx.x & 63;
  for (int it = 0; it < 16; ++it) {
    int r = it * 256 + wglob;
    const float* row = Wihd + (size_t)r * NH;
    float s = 0.f;
    for (int k = lane; k < NH; k += 64) s += row[k];
    for (int o = 32; o; o >>= 1) s += __shfl_down(s, o);
    if (lane == 0) bd0[r] = bd[r] + 0.1f * s;
  }
}

__global__ __launch_bounds__(256) void k_init(f16* hb, unsigned* bar) {
  int i = blockIdx.x * 256 + threadIdx.x;  // grid 1024 -> 262144
  hb[i] = (f16)0.f;
  if (i < 256) bar[i] = 0u;
}

// ---------------- generic NT GEMM (unchanged; passed R1) ----------------
template <int EPI>
__global__ __launch_bounds__(256) void k_gemm(const f16* __restrict__ A,
                                              const f16* __restrict__ Bm,
                                              const float* __restrict__ bias,
                                              f16* __restrict__ outH,
                                              float* __restrict__ outF,
                                              int M, int N, int K) {
  __shared__ char lds[32768];  // A 16KB @0, B 16KB @16384
  const int tid = threadIdx.x;
  const int lane = tid & 63, wid = tid >> 6;
  const int wm = wid >> 1, wn = wid & 1;
  const int bm = blockIdx.y * 128, bn = blockIdx.x * 128;
  const int l15 = lane & 15, l4 = lane >> 4;

  f32x4 acc[4][4] = {};

  for (int k0 = 0; k0 < K; k0 += 64) {
#pragma unroll
    for (int q = 0; q < 4; ++q) {
      int P = (q * 256 + tid) * 16;
      int L = swz(P);
      int row = L >> 7, col = (L & 127) >> 1;
      GL_LDS16(A + (size_t)(bm + row) * K + k0 + col, lds + P);
      GL_LDS16(Bm + (size_t)(bn + row) * K + k0 + col, lds + 16384 + P);
    }
    __syncthreads();
#pragma unroll
    for (int kk = 0; kk < 2; ++kk) {
      half8 af[4], bf[4];
#pragma unroll
      for (int mi = 0; mi < 4; ++mi) {
        int L = (wm * 64 + mi * 16 + l15) * 128 + (kk * 32 + l4 * 8) * 2;
        af[mi] = *(const half8*)(lds + swz(L));
      }
#pragma unroll
      for (int ni = 0; ni < 4; ++ni) {
        int L = (wn * 64 + ni * 16 + l15) * 128 + (kk * 32 + l4 * 8) * 2;
        bf[ni] = *(const half8*)(lds + 16384 + swz(L));
      }
#pragma unroll
      for (int mi = 0; mi < 4; ++mi)
#pragma unroll
        for (int ni = 0; ni < 4; ++ni)
          acc[mi][ni] = __builtin_amdgcn_mfma_f32_16x16x32_f16(af[mi], bf[ni], acc[mi][ni], 0, 0, 0);
    }
    __syncthreads();
  }

#pragma unroll
  for (int mi = 0; mi < 4; ++mi)
#pragma unroll
    for (int ni = 0; ni < 4; ++ni)
#pragma unroll
      for (int e = 0; e < 4; ++e) {
        int m = bm + wm * 64 + mi * 16 + l4 * 4 + e;
        int n = bn + wn * 64 + ni * 16 + l15;
        float v = acc[mi][ni][e] + bias[n];
        if constexpr (EPI == 0) {
          outH[(size_t)m * N + n] = (f16)v;
        } else {
          int b = m & 255, t = m >> 8;
          outF[(size_t)b * (NT * NZ) + t * NZ + n] = tanhf(v);
        }
      }
}

// ---------------- persistent recurrent kernel ----------------
// 256 blocks x 512 thr (8 waves), 86KB LDS -> EXACTLY 1 block/CU, so a
// cooperative launch places exactly 32 blocks on each of the 8 XCDs. Each
// block discovers its XCD (HW_REG_XCC_ID) and takes a rank 0..31 within it:
//   bg = xcd (owns batch rows bg*32..+32), ug = rank (owns units ug*32..+32).
// ALL cross-block dataflow (h slices) then stays inside ONE XCD's L2.
// CDNA vL1 is write-through, so after vmcnt(0) the h2 stores are in the
// shared L2; readers only need a CU-local vL1 invalidate (buffer_inv).
// Barrier counters use RELAXED agent-scope atomics (coherent-point ops, no
// L2 writeback/invalidate) -- this removes R4's 25us/step fence cost.
//
// LDS: A(h tile, swizzled) 64KB @0 | gate exch 16KB @65536 | c 4KB @81920 | grp @86016

__device__ __forceinline__ void loadW(half8* breg, const f16* __restrict__ W,
                                      int row, int l4) {
  const f16* p = W + (size_t)row * NH + l4 * 8;
#pragma unroll
  for (int kf = 0; kf < 32; ++kf) breg[kf] = *(const half8*)(p + kf * 32);
}

__device__ __forceinline__ void gsync(unsigned* bar, unsigned target) {
  asm volatile("s_waitcnt vmcnt(0)" ::: "memory");  // h2 stores drained to L2
  __syncthreads();
  if (threadIdx.x == 0) {
    __hip_atomic_fetch_add(bar, 1u, __ATOMIC_RELAXED, __HIP_MEMORY_SCOPE_AGENT);
    while (__hip_atomic_load(bar, __ATOMIC_RELAXED, __HIP_MEMORY_SCOPE_AGENT) < target) {}
  }
  __syncthreads();
  asm volatile("buffer_inv" ::: "memory");  // vL1 invalidate (CU-local, cheap)
}

template <bool ENC>
__device__ __forceinline__ void lstm_step(const f16* __restrict__ hi, f16* __restrict__ ho,
                                          const half8* breg, char* ldsb,
                                          const f16* __restrict__ xg0,
                                          const f16* __restrict__ xg1,
                                          const float* bias4, int bg, int ug, int tid,
                                          int l15, int l4, int g, int uh) {
  float pre[8];
  if constexpr (ENC) {  // issue early: HBM latency hides under staging+MFMA
#pragma unroll
    for (int i = 0; i < 4; ++i) {
      pre[i] = (float)xg0[i * 1024];
      pre[4 + i] = (float)xg1[i * 1024];
    }
  } else {
#pragma unroll
    for (int i = 0; i < 4; ++i) { pre[i] = bias4[i]; pre[4 + i] = bias4[i]; }
  }
  // stage h[bg*32 .. +32][0..1024] -> LDS A (linear dest, inverse-swizzled src)
#pragma unroll
  for (int it = 0; it < 8; ++it) {
    int P = (it * 512 + tid) * 16;
    int L = swza(P);
    GL_LDS16(hi + (size_t)(bg * 32 + (L >> 11)) * NH + ((L & 2047) >> 1), ldsb + P);
  }
  __syncthreads();

  f32x4 acc0 = {}, acc1 = {};
#pragma unroll
  for (int kf = 0; kf < 32; ++kf) {
    int L0 = l15 * 2048 + kf * 64 + l4 * 16;
    half8 a0 = *(const half8*)(ldsb + swza(L0));
    half8 a1 = *(const half8*)(ldsb + swza(L0 + 32768));
    acc0 = __builtin_amdgcn_mfma_f32_16x16x32_f16(a0, breg[kf], acc0, 0, 0, 0);
    acc1 = __builtin_amdgcn_mfma_f32_16x16x32_f16(a1, breg[kf], acc1, 0, 0, 0);
  }

  float* ex = (float*)(ldsb + 65536);  // [4 g][32 b][32 u]
  float* cc = (float*)(ldsb + 81920);  // [32 b][32 u]
#pragma unroll
  for (int e = 0; e < 4; ++e) {
    ex[g * 1024 + (l4 * 4 + e) * 32 + uh * 16 + l15] = acc0[e];
    ex[g * 1024 + (16 + l4 * 4 + e) * 32 + uh * 16 + l15] = acc1[e];
  }
  __syncthreads();

#pragma unroll
  for (int hf = 0; hf < 2; ++hf) {
    int ci = hf * 512 + tid;  // b = ci>>5, u = ci&31
    float v0 = ex[ci] + pre[hf * 4 + 0];
    float v1 = ex[1024 + ci] + pre[hf * 4 + 1];
    float v2 = ex[2048 + ci] + pre[hf * 4 + 2];
    float v3 = ex[3072 + ci] + pre[hf * 4 + 3];
    float i_ = sigm(v0), f_ = sigm(v1), gg = tanhf(v2), o_ = sigm(v3);
    float c2 = f_ * cc[ci] + i_ * gg;
    cc[ci] = c2;
    ho[(size_t)(bg * 32 + (ci >> 5)) * NH + ug * 32 + (ci & 31)] = (f16)(o_ * tanhf(c2));
  }
}

__global__ __launch_bounds__(512, 2) void k_rnn(const f16* __restrict__ Whhe,
                                                const f16* __restrict__ Whhd,
                                                const f16* __restrict__ Wsum,
                                                const f16* __restrict__ Xg,
                                                const float* __restrict__ bd0v,
                                                const float* __restrict__ bdv,
                                                f16* __restrict__ hb0,
                                                f16* __restrict__ hb1,
                                                f16* __restrict__ Hs,
                                                unsigned* bar) {
  __shared__ __align__(16) char ldsb[86048];
  const int tid = threadIdx.x, lane = tid & 63, wid = tid >> 6;
  const int l15 = lane & 15, l4 = lane >> 4;
  const int g = wid >> 1, uh = wid & 1;
  const int u0 = tid & 31, b0 = tid >> 5;

  // ---- discover physical XCD and take a rank within it ----
  unsigned* sgrp = (unsigned*)(ldsb + 86016);
  if (tid == 0) {
    unsigned xcd;
    asm volatile("s_getreg_b32 %0, hwreg(HW_REG_XCC_ID)" : "=s"(xcd));
    xcd &= 7;
    unsigned rank = __hip_atomic_fetch_add(bar + xcd * 32 + 16, 1u,
                                           __ATOMIC_RELAXED, __HIP_MEMORY_SCOPE_AGENT);
    sgrp[0] = xcd;
    sgrp[1] = rank & 31;
  }
  float* cc = (float*)(ldsb + 81920);
  cc[tid] = 0.f;
  cc[512 + tid] = 0.f;
  __syncthreads();
  const int bg = sgrp[0], ug = sgrp[1];

  unsigned* mybar = bar + bg * 32;  // 8 counters, 128B apart (rank ctr at +16)
  unsigned gen = 0;
  const int wrow = g * 1024 + ug * 32 + uh * 16 + l15;

  half8 breg[32];
  loadW(breg, Whhe, wrow, l4);

  // -------- encoder: 64 steps, h ping-pong hb0/hb1 --------
  f16* hi = hb0;
  f16* ho = hb1;
  for (int t = 0; t < NT; ++t) {
    const f16* xg0 = Xg + ((size_t)(bg * 32 + b0) * NT + t) * NG + ug * 32 + u0;
    const f16* xg1 = xg0 + (size_t)16 * NT * NG;
    lstm_step<true>(hi, ho, breg, ldsb, xg0, xg1, nullptr, bg, ug, tid, l15, l4, g, uh);
    ++gen;
    gsync(mybar, gen * 32u);
    f16* tmp = hi; hi = ho; ho = tmp;
  }
  // encoder final h now in hi (= hb0)

  // -------- decoder step 0: W_hh_d, bias bd0 (0.1-input folded) --------
  loadW(breg, Whhd, wrow, l4);
  float bias4[4];
#pragma unroll
  for (int i = 0; i < 4; ++i) bias4[i] = bd0v[i * 1024 + ug * 32 + u0];
  lstm_step<false>(hi, Hs, breg, ldsb, nullptr, nullptr, bias4, bg, ug, tid, l15, l4, g, uh);
  ++gen;
  gsync(mybar, gen * 32u);

  // -------- decoder steps 1..63: W_ih_d + W_hh_d (inp == h), bias bd --------
  loadW(breg, Wsum, wrow, l4);
#pragma unroll
  for (int i = 0; i < 4; ++i) bias4[i] = bdv[i * 1024 + ug * 32 + u0];
  for (int t = 1; t < NT; ++t) {
    lstm_step<false>(Hs + (size_t)(t - 1) * NB * NH, Hs + (size_t)t * NB * NH, breg, ldsb,
                     nullptr, nullptr, bias4, bg, ug, tid, l15, l4, g, uh);
    if (t != NT - 1) {
      ++gen;
      gsync(mybar, gen * 32u);
    }
  }
}

// ---------------- workspace layout ----------------
// x16 (32MB) is dead after k_gemm<0>; Hs [T][B][H] fp16 (exactly 32MB) reuses it.
static const size_t OFF_X16  = 0;
static const size_t OFF_WIHE = OFF_X16 + (size_t)NB * NT * NE * 2;
static const size_t OFF_WHHE = OFF_WIHE + (size_t)NG * NH * 2;
static const size_t OFF_WSUM = OFF_WHHE + (size_t)NG * NH * 2;
static const size_t OFF_WHHD = OFF_WSUM + (size_t)NG * NH * 2;
static const size_t OFF_WZ   = OFF_WHHD + (size_t)NG * NH * 2;
static const size_t OFF_BE   = OFF_WZ + (size_t)NZ * NH * 2;
static const size_t OFF_BD   = OFF_BE + NG * 4;
static const size_t OFF_BD0  = OFF_BD + NG * 4;
static const size_t OFF_HB0  = OFF_BD0 + NG * 4;
static const size_t OFF_HB1  = OFF_HB0 + (size_t)NB * NH * 2;
static const size_t OFF_BAR  = OFF_HB1 + (size_t)NB * NH * 2;
static const size_t OFF_XG   = OFF_BAR + 4096;  // Xg [B][T][4H] fp16 (read-only in k_rnn)
static const size_t WS_TOTAL = OFF_XG + (size_t)NB * NT * NG * 2;  // ~193 MiB

extern "C" void kernel_launch(void* const* d_in, const int* in_sizes, int n_in,
                              void* d_out, int out_size, void* d_ws, size_t ws_size,
                              hipStream_t stream) {
  (void)in_sizes; (void)n_in; (void)out_size;
  const float* x    = (const float*)d_in[0];
  const float* Wihe = (const float*)d_in[1];
  const float* Whhe = (const float*)d_in[2];
  const float* bihe = (const float*)d_in[3];
  const float* bhhe = (const float*)d_in[4];
  const float* Wihd = (const float*)d_in[5];
  const float* Whhd = (const float*)d_in[6];
  const float* bihd = (const float*)d_in[7];
  const float* bhhd = (const float*)d_in[8];
  const float* Wzf  = (const float*)d_in[9];
  const float* bz   = (const float*)d_in[10];
  float* out = (float*)d_out;

  if (ws_size < WS_TOTAL) return;

  char* ws = (char*)d_ws;
  f16* x16    = (f16*)(ws + OFF_X16);
  f16* Wihe16 = (f16*)(ws + OFF_WIHE);
  f16* Whhe16 = (f16*)(ws + OFF_WHHE);
  f16* Wsum16 = (f16*)(ws + OFF_WSUM);
  f16* Whhd16 = (f16*)(ws + OFF_WHHD);
  f16* Wz16   = (f16*)(ws + OFF_WZ);
  float* be   = (float*)(ws + OFF_BE);
  float* bd   = (float*)(ws + OFF_BD);
  float* bd0  = (float*)(ws + OFF_BD0);
  f16* hb0    = (f16*)(ws + OFF_HB0);
  f16* hb1    = (f16*)(ws + OFF_HB1);
  unsigned* bar = (unsigned*)(ws + OFF_BAR);
  f16* Xg     = (f16*)(ws + OFF_XG);
  f16* Hs     = x16;  // decoder h history overlays dead x16 (NOT Xg — R2 bug)

  // prep
  k_cvt<<<(NB * NT * NE) / 1024, 256, 0, stream>>>(x, x16);
  k_cvt<<<(NG * NH) / 1024, 256, 0, stream>>>(Wihe, Wihe16);
  k_cvt<<<(NG * NH) / 1024, 256, 0, stream>>>(Whhe, Whhe16);
  k_cvt<<<(NG * NH) / 1024, 256, 0, stream>>>(Whhd, Whhd16);
  k_cvt<<<(NZ * NH) / 1024, 256, 0, stream>>>(Wzf, Wz16);
  k_addcvt<<<(NG * NH) / 1024, 256, 0, stream>>>(Wihd, Whhd, Wsum16);
  k_bias<<<NG / 256, 256, 0, stream>>>(bihe, bhhe, bihd, bhhd, be, bd);
  k_bd0<<<64, 256, 0, stream>>>(Wihd, bd, bd0);
  k_init<<<(NB * NH) / 256, 256, 0, stream>>>(hb0, bar);

  // Xg = x @ W_ih_e^T + be   -> fp16 [B][T][4H]
  dim3 gx(NG / 128, (NB * NT) / 128);
  k_gemm<0><<<gx, 256, 0, stream>>>(x16, Wihe16, be, Xg, nullptr, NB * NT, NG, NE);

  // persistent recurrent kernel (cooperative: guarantees co-residency for barriers)
  void* kargs[10];
  kargs[0] = &Whhe16; kargs[1] = &Whhd16; kargs[2] = &Wsum16; kargs[3] = &Xg;
  kargs[4] = &bd0; kargs[5] = &bd; kargs[6] = &hb0; kargs[7] = &hb1;
  kargs[8] = &Hs; kargs[9] = &bar;
  hipLaunchCooperativeKernel((const void*)k_rnn, dim3(256), dim3(512), kargs, 0, stream);

  // z = tanh(Hs @ Wz^T + bz), scattered [t*256+b] -> out[b][t][:]
  dim3 gz(NZ / 128, (NB * NT) / 128);
  k_gemm<1><<<gz, 256, 0, stream>>>(Hs, Wz16, bz, nullptr, out, NB * NT, NZ, NH);
}